// Round 1
// baseline (1527.465 us; speedup 1.0000x reference)
//
#include <hip/hip_runtime.h>
#include <cstdint>

typedef __bf16 bf16x8 __attribute__((ext_vector_type(8)));
typedef float floatx4 __attribute__((ext_vector_type(4)));
typedef unsigned int uint4v __attribute__((ext_vector_type(4)));
typedef unsigned int uint2v __attribute__((ext_vector_type(2)));
using u16 = unsigned short;

#define DEVFN static __device__ __forceinline__

// ---------------- workspace layout (bytes) ----------------
// required ws_size >= ~279 MB
#define SZ_BIG   134217728ull                 // 8*4096*2048 bf16
#define OFF_YT   0ull                         // Yt [b][j=(t,c)][n] bf16
#define OFF_T1N  0ull                         // T1n reuses Yt region (Yt dead by then)
#define OFF_T1T  SZ_BIG                       // T1t [b][j][m] bf16
#define OFF_LBF  (2ull*SZ_BIG)                // L bf16 [m][n]
#define OFF_W1SW (OFF_LBF + 8388608ull)       // conv1 A-operand, MFMA-frag-swizzled, 12288 B
#define OFF_GSW  (OFF_W1SW + 12288ull)        // fused-stage G, frag-swizzled, 3*24576 B
#define OFF_P    (OFF_GSW + 73728ull)         // P[t'][dt] cheb_b feed-through, 768 B
#define OFF_AB   (OFF_P + 1024ull)            // BN scale/shift, 512 B
#define OFF_S    (OFF_P + 2048ull)            // stat partials sum [64][4096] f32
#define OFF_S2   (OFF_S + 1048576ull)         // stat partials sumsq

DEVFN u16 f2bf(float f) {
  unsigned u = __builtin_bit_cast(unsigned, f);
  unsigned r = u + 0x7fffu + ((u >> 16) & 1u);   // RNE
  return (u16)(r >> 16);
}
DEVFN bf16x8 as_bf(uint4v v) { union { uint4v u; bf16x8 b; } x; x.u = v; return x.b; }

DEVFN void gld16(const void* g, void* l) {
  __builtin_amdgcn_global_load_lds(
      (const __attribute__((address_space(1))) void*)(uintptr_t)g,
      (__attribute__((address_space(3))) void*)(unsigned)(uintptr_t)l,
      16, 0, 0);
}

// ---------------- prep: swizzle w1 into MFMA-A order; cheb_b feed-through P ----------------
__global__ __launch_bounds__(256) void k_prep1(const float* w1, const float* w2,
                                               const float* chb, char* ws) {
  u16* W1sw = (u16*)(ws + OFF_W1SW);
  float* P  = (float*)(ws + OFF_P);
  int tid = threadIdx.x;
  for (int it = 0; it < 24; ++it) {
    int idx = it * 256 + tid;                    // < 6144
    int i = idx & 7, lane = (idx >> 3) & 63, trow = (idx >> 9) & 3, h = idx >> 11;
    int m = trow * 16 + (lane & 15);
    int k = h * 32 + (lane >> 4) * 8 + i;        // < 96
    W1sw[idx] = f2bf(w1[(m * 32 + (k & 31)) * 3 + (k >> 5)]);
  }
  if (tid < 192) {
    int tp = tid / 3, dt = tid % 3;
    float s = 0.f;
    for (int d = 0; d < 64; ++d) s += w2[(tp * 64 + d) * 3 + dt] * chb[d];
    P[tid] = s;
  }
}

// ---------------- prep: G_i[t'][dt*64+c] = sum_d w2[t',d,dt]*A_i[c,d], frag-swizzled ----------------
__global__ __launch_bounds__(256) void k_prepG(const float* w2, const float* chw, char* ws) {
  u16* Gsw = (u16*)(ws + OFF_GSW);
  int s = blockIdx.x >> 6, tp = blockIdx.x & 63;
  int tid = threadIdx.x;
  if (tid >= 192) return;
  int dt = tid >> 6, c = tid & 63;
  float acc = 0.f;
  for (int d = 0; d < 64; ++d) {
    float a;
    if (s == 0)      a = chw[(0 * 64 + c) * 64 + d] - chw[(2 * 64 + c) * 64 + d];
    else if (s == 1) a = chw[(1 * 64 + c) * 64 + d];
    else             a = 2.f * chw[(2 * 64 + c) * 64 + d];
    acc += w2[(tp * 64 + d) * 3 + dt] * a;
  }
  int h = tid >> 5, k32 = tid & 31;
  int lane = (k32 >> 3) * 16 + (tp & 15), trow = tp >> 4;
  Gsw[(size_t)(((s * 6 + h) * 4 + trow) * 64 + lane) * 8 + (k32 & 7)] = f2bf(acc);
}

// ---------------- cast L -> bf16 ----------------
__global__ __launch_bounds__(256) void k_castL(const float* L, char* ws) {
  u16* Lbf = (u16*)(ws + OFF_LBF);
  size_t i = ((size_t)blockIdx.x * 256 + threadIdx.x) * 4;
  float4 v = *(const float4*)(L + i);
  uint2v o;
  o.x = f2bf(v.x) | ((unsigned)f2bf(v.y) << 16);
  o.y = f2bf(v.z) | ((unsigned)f2bf(v.w) << 16);
  *(uint2v*)(Lbf + i) = o;
}

// ---------------- conv1 (MFMA): Yt[b][t*64+c][n] = b1[t] + sum x[b,n,c-1+dt,cin]*w1 ----------------
__global__ __launch_bounds__(256) void k_conv1(const float* x, const float* b1, char* ws) {
  __shared__ u16 Wl[6144];          // 12,288 B swizzled A
  __shared__ u16 Xt[128 * 104];     // rows padded to 104 elems (208 B) for bank balance
  int tid = threadIdx.x, bx = blockIdx.x;
  int nt = bx & 15, ct = (bx >> 4) & 63, b = bx >> 10;
  int n0 = nt * 128;
  const char* wsrc = ws + OFF_W1SW;
  for (int e = 0; e < 3; ++e) {
    int flat = e * 256 + tid;
    gld16(wsrc + flat * 16, (char*)Wl + flat * 16);
  }
  const float* xb = x + ((size_t)(b * 2048 + n0)) * 2048;
  for (int e = 0; e < 12; ++e) {
    int f = e * 256 + tid;
    int nl = f / 24, c4 = f % 24;
    int eo = ct * 32 - 32 + c4 * 4;
    uint2v o = {0u, 0u};
    if (eo >= 0 && eo < 2048) {
      float4 v = *(const float4*)(xb + (size_t)nl * 2048 + eo);
      o.x = f2bf(v.x) | ((unsigned)f2bf(v.y) << 16);
      o.y = f2bf(v.z) | ((unsigned)f2bf(v.w) << 16);
    }
    *(uint2v*)&Xt[nl * 104 + c4 * 4] = o;
  }
  __syncthreads();
  int w = tid >> 6, l = tid & 63, lm = l & 15, q = l >> 4;
  floatx4 zf = {0.f, 0.f, 0.f, 0.f};
  floatx4 acc[4][2];
  for (int s = 0; s < 4; ++s) for (int t = 0; t < 2; ++t) acc[s][t] = zf;
  for (int h = 0; h < 3; ++h) {
    bf16x8 a[4], bb[2];
    for (int s = 0; s < 4; ++s)
      a[s] = as_bf(*(const uint4v*)&Wl[(size_t)((h * 4 + s) * 64 + l) * 8]);
    for (int t = 0; t < 2; ++t) {
      int n = w * 32 + t * 16 + lm;
      bb[t] = as_bf(*(const uint4v*)&Xt[n * 104 + h * 32 + q * 8]);
    }
    for (int s = 0; s < 4; ++s)
      for (int t = 0; t < 2; ++t)
        acc[s][t] = __builtin_amdgcn_mfma_f32_16x16x32_bf16(a[s], bb[t], acc[s][t], 0, 0, 0);
  }
  u16* Yt = (u16*)(ws + OFF_YT);
  for (int s = 0; s < 4; ++s)
    for (int r = 0; r < 4; ++r) {
      int tch = s * 16 + q * 4 + r;
      float bias = b1[tch];
      for (int t = 0; t < 2; ++t) {
        int n = n0 + w * 32 + t * 16 + lm;
        Yt[(size_t)(b * 4096 + tch * 64 + ct) * 2048 + n] = f2bf(acc[s][t][r] + bias);
      }
    }
}

// ---------------- big GEMM: C[r][c] = sum_k P[r][k]*Q[c][k], K=2048, bf16, 128x128 tile ----------------
__global__ __launch_bounds__(256) void k_gemm(const char* Pbase, const char* Qbase, char* Cbase,
                                              int MT, size_t P_bs, size_t Q_bs,
                                              size_t C_bs, size_t C_rs) {
  __shared__ u16 Pt[128 * 32];
  __shared__ u16 Qt[128 * 32];
  int tid = threadIdx.x, b = blockIdx.y;
  int rt = blockIdx.x % MT, ctl = blockIdx.x / MT;
  const char* Pp = Pbase + b * P_bs + (size_t)rt * 128 * 4096;
  const char* Qp = Qbase + b * Q_bs + (size_t)ctl * 128 * 4096;
  int w = tid >> 6, l = tid & 63, lm = l & 15, q = l >> 4;
  int wr = (w & 1) * 64, wc = (w >> 1) * 64;
  floatx4 zf = {0.f, 0.f, 0.f, 0.f};
  floatx4 acc[4][4];
  for (int s = 0; s < 4; ++s) for (int t = 0; t < 4; ++t) acc[s][t] = zf;
  for (int k0 = 0; k0 < 2048; k0 += 32) {
    for (int e = 0; e < 2; ++e) {
      int flat = e * 256 + tid;
      int row = flat >> 2, off = (flat & 3) * 16;
      gld16(Pp + (size_t)row * 4096 + k0 * 2 + off, (char*)Pt + flat * 16);
      gld16(Qp + (size_t)row * 4096 + k0 * 2 + off, (char*)Qt + flat * 16);
    }
    __syncthreads();
    bf16x8 a[4], bb[4];
    for (int s = 0; s < 4; ++s) a[s]  = as_bf(*(const uint4v*)&Pt[(wr + s * 16 + lm) * 32 + q * 8]);
    for (int t = 0; t < 4; ++t) bb[t] = as_bf(*(const uint4v*)&Qt[(wc + t * 16 + lm) * 32 + q * 8]);
    for (int s = 0; s < 4; ++s)
      for (int t = 0; t < 4; ++t)
        acc[s][t] = __builtin_amdgcn_mfma_f32_16x16x32_bf16(a[s], bb[t], acc[s][t], 0, 0, 0);
    __syncthreads();
  }
  for (int s = 0; s < 4; ++s)
    for (int r = 0; r < 4; ++r) {
      size_t rg = (size_t)rt * 128 + wr + s * 16 + q * 4 + r;
      char* crow = Cbase + b * C_bs + rg * C_rs;
      for (int t = 0; t < 4; ++t) {
        size_t cg = (size_t)ctl * 128 + wc + t * 16 + lm;
        *(u16*)(crow + cg * 2) = f2bf(acc[s][t][r]);
      }
    }
}

// ---------------- 64x64 LDS tile transpose: out[b][n][j] = in[b][j][n] (bf16) ----------------
__global__ __launch_bounds__(256) void k_transpose(const char* in, size_t in_bs,
                                                   char* out, size_t out_bs, size_t out_rs) {
  __shared__ u16 LT[64 * 74];
  int tid = threadIdx.x, b = blockIdx.y;
  int jt = blockIdx.x & 63, nt = blockIdx.x >> 6;
  int j0 = jt * 64, n0 = nt * 64;
  for (int e = 0; e < 2; ++e) {
    int flat = e * 256 + tid;
    int jl = flat >> 3, nc = (flat & 7) * 8;
    uint4v v = *(const uint4v*)(in + b * in_bs + (size_t)(j0 + jl) * 4096 + (n0 + nc) * 2);
    u16 u[8] = {(u16)(v.x & 0xffff), (u16)(v.x >> 16), (u16)(v.y & 0xffff), (u16)(v.y >> 16),
                (u16)(v.z & 0xffff), (u16)(v.z >> 16), (u16)(v.w & 0xffff), (u16)(v.w >> 16)};
    for (int i = 0; i < 8; ++i) LT[(nc + i) * 74 + jl] = u[i];
  }
  __syncthreads();
  for (int e = 0; e < 2; ++e) {
    int flat = e * 256 + tid;
    int nl = flat >> 3, jc = (flat & 7) * 8;
    unsigned p[4];
    for (int i = 0; i < 4; ++i) {
      unsigned lo = LT[nl * 74 + jc + 2 * i], hi = LT[nl * 74 + jc + 2 * i + 1];
      p[i] = lo | (hi << 16);
    }
    uint4v v = {p[0], p[1], p[2], p[3]};
    *(uint4v*)(out + b * out_bs + (size_t)(n0 + nl) * out_rs + (j0 + jc) * 2) = v;
  }
}

// ---------------- fused cheb-projection + conv2: out2[b,n,t',c'] (fp32, final layout) ----------------
__global__ __launch_bounds__(256) void k_fused(char* ws, float* dout, const float* b2) {
  __shared__ u16 Gs[12288];          // 24,576 B one source's swizzled G
  __shared__ u16 Brow[2][4752];      // 66 groups * (64 elems + 16B pad) per row, 2 rows
  int tid = threadIdx.x;
  int np = blockIdx.x, b = blockIdx.y;
  size_t row0 = (size_t)b * 2048 + np * 2;
  if (tid < 144) {                   // zero LDS guard groups (conv SAME padding)
    int r = tid / 72, o = tid % 72;
    Brow[r][o] = 0; Brow[r][65 * 72 + o] = 0;
  }
  int w = tid >> 6, l = tid & 63, lm = l & 15, q = l >> 4;
  int n_loc = w & 1, thalf = w >> 1;
  floatx4 zf = {0.f, 0.f, 0.f, 0.f};
  floatx4 acc[2][4];
  for (int tr = 0; tr < 2; ++tr) for (int tc = 0; tc < 4; ++tc) acc[tr][tc] = zf;
  for (int s = 0; s < 3; ++s) {
    for (int e = 0; e < 6; ++e) {
      int flat = e * 256 + tid;
      gld16(ws + OFF_GSW + (size_t)s * 24576 + flat * 16, (char*)Gs + flat * 16);
    }
    for (int e = 0; e < 4; ++e) {
      int ci = e * 256 + tid;              // 0..1023
      int rl = ci >> 9, c = ci & 511;
      size_t rid = row0 + rl;
      const char* src;
      if (s == 0)      src = (const char*)dout + rid * 16384;           // Yn
      else if (s == 1) src = ws + OFF_T1N + rid * 8192;                 // T1n
      else             src = (const char*)dout + rid * 16384 + 8192;    // Un
      uint4v v = *(const uint4v*)(src + c * 16);
      int e0 = 64 + c * 8;
      *(uint4v*)&Brow[rl][(e0 >> 6) * 72 + (e0 & 63)] = v;
    }
    __syncthreads();
    for (int h = 0; h < 6; ++h) {
      int dt = h >> 1, chalf = h & 1;
      bf16x8 a[2], bb[4];
      for (int tr = 0; tr < 2; ++tr)
        a[tr] = as_bf(*(const uint4v*)&Gs[(size_t)((h * 4 + thalf * 2 + tr) * 64 + l) * 8]);
      for (int tc = 0; tc < 4; ++tc) {
        int cp = tc * 16 + lm;
        int ctil = cp + dt;
        bb[tc] = as_bf(*(const uint4v*)&Brow[n_loc][ctil * 72 + chalf * 32 + q * 8]);
      }
      for (int tr = 0; tr < 2; ++tr)
        for (int tc = 0; tc < 4; ++tc)
          acc[tr][tc] = __builtin_amdgcn_mfma_f32_16x16x32_bf16(a[tr], bb[tc], acc[tr][tc], 0, 0, 0);
    }
    __syncthreads();
  }
  const float* P = (const float*)(ws + OFF_P);
  float* orow = dout + (row0 + n_loc) * 4096;
  for (int tr = 0; tr < 2; ++tr)
    for (int r = 0; r < 4; ++r) {
      int tp = thalf * 32 + tr * 16 + q * 4 + r;
      float base = b2[tp] + P[tp * 3 + 1];
      for (int tc = 0; tc < 4; ++tc) {
        int cp = tc * 16 + lm;
        float bias = base + (cp > 0 ? P[tp * 3] : 0.f) + (cp < 63 ? P[tp * 3 + 2] : 0.f);
        orow[tp * 64 + cp] = acc[tr][tc][r] + bias;
      }
    }
}

// ---------------- BN stats: per-block partials per channel ----------------
__global__ __launch_bounds__(256) void k_stats(const float* dout, char* ws) {
  __shared__ float ls[256][8];
  int tid = threadIdx.x;
  size_t base = (size_t)blockIdx.x * 16384 + tid * 4;
  float s0 = 0, s1 = 0, s2 = 0, s3 = 0, t0 = 0, t1 = 0, t2 = 0, t3 = 0;
  for (int it = 0; it < 16; ++it) {
    float4 v = *(const float4*)(dout + base + (size_t)it * 1024);
    s0 += v.x; s1 += v.y; s2 += v.z; s3 += v.w;
    t0 += v.x * v.x; t1 += v.y * v.y; t2 += v.z * v.z; t3 += v.w * v.w;
  }
  ls[tid][0] = s0; ls[tid][1] = s1; ls[tid][2] = s2; ls[tid][3] = s3;
  ls[tid][4] = t0; ls[tid][5] = t1; ls[tid][6] = t2; ls[tid][7] = t3;
  __syncthreads();
  if (tid < 64) {
    int g = tid >> 2, sl = tid & 3;
    float S = 0, S2 = 0;
    for (int j = 0; j < 16; ++j) { S += ls[g + j * 16][sl]; S2 += ls[g + j * 16][4 + sl]; }
    ((float*)(ws + OFF_S))[(size_t)tid * 4096 + blockIdx.x] = S;
    ((float*)(ws + OFF_S2))[(size_t)tid * 4096 + blockIdx.x] = S2;
  }
}

__global__ __launch_bounds__(256) void k_statsf(char* ws, const float* gamma, const float* beta) {
  __shared__ float red[256];
  int c = blockIdx.x, tid = threadIdx.x;
  const float* S  = (const float*)(ws + OFF_S)  + (size_t)c * 4096;
  const float* S2 = (const float*)(ws + OFF_S2) + (size_t)c * 4096;
  float a = 0, bsum = 0;
  for (int j = 0; j < 16; ++j) { a += S[tid + j * 256]; bsum += S2[tid + j * 256]; }
  red[tid] = a; __syncthreads();
  for (int st = 128; st > 0; st >>= 1) { if (tid < st) red[tid] += red[tid + st]; __syncthreads(); }
  float Ssum = red[0]; __syncthreads();
  red[tid] = bsum; __syncthreads();
  for (int st = 128; st > 0; st >>= 1) { if (tid < st) red[tid] += red[tid + st]; __syncthreads(); }
  if (tid == 0) {
    float S2sum = red[0];
    float mean = Ssum / 1048576.f;
    float var = S2sum / 1048576.f - mean * mean;
    float inv = rsqrtf(var + 1e-5f);
    float A = gamma[c] * inv;
    float* AB = (float*)(ws + OFF_AB);
    AB[c] = A; AB[64 + c] = beta[c] - mean * A;
  }
}

__global__ __launch_bounds__(256) void k_bn(float* dout, const char* ws) {
  __shared__ float AB[128];
  int tid = threadIdx.x;
  if (tid < 128) AB[tid] = ((const float*)(ws + OFF_AB))[tid];
  __syncthreads();
  size_t i = ((size_t)blockIdx.x * 256 + tid) * 4;
  int c0 = (tid * 4) & 63;
  float4 v = *(const float4*)(dout + i);
  v.x = fmaxf(0.f, v.x * AB[c0]     + AB[64 + c0]);
  v.y = fmaxf(0.f, v.y * AB[c0 + 1] + AB[64 + c0 + 1]);
  v.z = fmaxf(0.f, v.z * AB[c0 + 2] + AB[64 + c0 + 2]);
  v.w = fmaxf(0.f, v.w * AB[c0 + 3] + AB[64 + c0 + 3]);
  *(float4*)(dout + i) = v;
}

extern "C" void kernel_launch(void* const* d_in, const int* in_sizes, int n_in,
                              void* d_out, int out_size, void* d_ws, size_t ws_size,
                              hipStream_t stream) {
  const float* x   = (const float*)d_in[0];
  const float* L   = (const float*)d_in[1];
  const float* w1  = (const float*)d_in[2];
  const float* b1  = (const float*)d_in[3];
  const float* chw = (const float*)d_in[4];
  const float* chb = (const float*)d_in[5];
  const float* w2  = (const float*)d_in[6];
  const float* b2  = (const float*)d_in[7];
  const float* gam = (const float*)d_in[8];
  const float* bet = (const float*)d_in[9];
  char* ws = (char*)d_ws;
  float* out = (float*)d_out;

  k_prep1<<<1, 256, 0, stream>>>(w1, w2, chb, ws);
  k_prepG<<<192, 256, 0, stream>>>(w2, chw, ws);
  k_castL<<<4096, 256, 0, stream>>>(L, ws);
  k_conv1<<<8192, 256, 0, stream>>>(x, b1, ws);
  // GEMM1: T1t[b][j][m] = sum_n Yt[b][j][n] * L[m][n]
  k_gemm<<<dim3(512, 8), 256, 0, stream>>>(ws + OFF_YT, ws + OFF_LBF, ws + OFF_T1T,
                                           32, (size_t)16777216, (size_t)0,
                                           (size_t)16777216, (size_t)4096);
  // GEMM2: Un[b][m'][j] = sum_m L[m'][m] * T1t[b][j][m]  -> d_out rows, second 8KB half
  k_gemm<<<dim3(512, 8), 256, 0, stream>>>(ws + OFF_LBF, ws + OFF_T1T, (char*)d_out + 8192,
                                           16, (size_t)0, (size_t)16777216,
                                           (size_t)33554432, (size_t)16384);
  // Yt -> Yn (d_out rows, first 8KB half)
  k_transpose<<<dim3(2048, 8), 256, 0, stream>>>(ws + OFF_YT, (size_t)16777216,
                                                 (char*)d_out, (size_t)33554432, (size_t)16384);
  // T1t -> T1n (ws @0, over dead Yt)
  k_transpose<<<dim3(2048, 8), 256, 0, stream>>>(ws + OFF_T1T, (size_t)16777216,
                                                 ws + OFF_T1N, (size_t)16777216, (size_t)8192);
  k_fused<<<dim3(1024, 8), 256, 0, stream>>>(ws, out, b2);
  k_stats<<<4096, 256, 0, stream>>>(out, ws);
  k_statsf<<<64, 256, 0, stream>>>(ws, gam, bet);
  k_bn<<<65536, 256, 0, stream>>>(out, ws);
}

// Round 2
// 1466.854 us; speedup vs baseline: 1.0413x; 1.0413x over previous
//
#include <hip/hip_runtime.h>
#include <cstdint>

typedef __bf16 bf16x8 __attribute__((ext_vector_type(8)));
typedef float floatx4 __attribute__((ext_vector_type(4)));
typedef unsigned int uint4v __attribute__((ext_vector_type(4)));
typedef unsigned int uint2v __attribute__((ext_vector_type(2)));
using u16 = unsigned short;

#define DEVFN static __device__ __forceinline__

// ---------------- workspace layout (bytes) ----------------
// required ws_size >= ~279 MB
#define SZ_BIG   134217728ull                 // 8*4096*2048 bf16
#define OFF_YT   0ull                         // Yt [b][j=(t,c)][n] bf16
#define OFF_T1N  0ull                         // T1n reuses Yt region (Yt dead by then)
#define OFF_T1T  SZ_BIG                       // T1t [b][j][m] bf16
#define OFF_LBF  (2ull*SZ_BIG)                // L bf16 [m][n]
#define OFF_W1SW (OFF_LBF + 8388608ull)       // conv1 A-operand, MFMA-frag-swizzled, 12288 B
#define OFF_GSW  (OFF_W1SW + 12288ull)        // fused-stage G, frag-swizzled, 3*24576 B
#define OFF_P    (OFF_GSW + 73728ull)         // P[t'][dt] cheb_b feed-through, 768 B
#define OFF_AB   (OFF_P + 1024ull)            // BN scale/shift, 512 B
#define OFF_S    (OFF_P + 2048ull)            // stat partials sum [64][4096] f32
#define OFF_S2   (OFF_S + 1048576ull)         // stat partials sumsq

DEVFN u16 f2bf(float f) {
  unsigned u = __builtin_bit_cast(unsigned, f);
  unsigned r = u + 0x7fffu + ((u >> 16) & 1u);   // RNE
  return (u16)(r >> 16);
}
DEVFN bf16x8 as_bf(uint4v v) { union { uint4v u; bf16x8 b; } x; x.u = v; return x.b; }

DEVFN void gld16(const void* g, void* l) {
  __builtin_amdgcn_global_load_lds(
      (const __attribute__((address_space(1))) void*)(uintptr_t)g,
      (__attribute__((address_space(3))) void*)(unsigned)(uintptr_t)l,
      16, 0, 0);
}

// ---------------- prep: swizzle w1 into MFMA-A order; cheb_b feed-through P ----------------
__global__ __launch_bounds__(256) void k_prep1(const float* w1, const float* w2,
                                               const float* chb, char* ws) {
  u16* W1sw = (u16*)(ws + OFF_W1SW);
  float* P  = (float*)(ws + OFF_P);
  int tid = threadIdx.x;
  for (int it = 0; it < 24; ++it) {
    int idx = it * 256 + tid;                    // < 6144
    int i = idx & 7, lane = (idx >> 3) & 63, trow = (idx >> 9) & 3, h = idx >> 11;
    int m = trow * 16 + (lane & 15);
    int k = h * 32 + (lane >> 4) * 8 + i;        // < 96
    W1sw[idx] = f2bf(w1[(m * 32 + (k & 31)) * 3 + (k >> 5)]);
  }
  if (tid < 192) {
    int tp = tid / 3, dt = tid % 3;
    float s = 0.f;
    for (int d = 0; d < 64; ++d) s += w2[(tp * 64 + d) * 3 + dt] * chb[d];
    P[tid] = s;
  }
}

// ---------------- prep: G_i[t'][dt*64+c] = sum_d w2[t',d,dt]*A_i[c,d], frag-swizzled ----------------
__global__ __launch_bounds__(256) void k_prepG(const float* w2, const float* chw, char* ws) {
  u16* Gsw = (u16*)(ws + OFF_GSW);
  int s = blockIdx.x >> 6, tp = blockIdx.x & 63;
  int tid = threadIdx.x;
  if (tid >= 192) return;
  int dt = tid >> 6, c = tid & 63;
  float acc = 0.f;
  for (int d = 0; d < 64; ++d) {
    float a;
    if (s == 0)      a = chw[(0 * 64 + c) * 64 + d] - chw[(2 * 64 + c) * 64 + d];
    else if (s == 1) a = chw[(1 * 64 + c) * 64 + d];
    else             a = 2.f * chw[(2 * 64 + c) * 64 + d];
    acc += w2[(tp * 64 + d) * 3 + dt] * a;
  }
  int h = tid >> 5, k32 = tid & 31;
  int lane = (k32 >> 3) * 16 + (tp & 15), trow = tp >> 4;
  Gsw[(size_t)(((s * 6 + h) * 4 + trow) * 64 + lane) * 8 + (k32 & 7)] = f2bf(acc);
}

// ---------------- cast L -> bf16 ----------------
__global__ __launch_bounds__(256) void k_castL(const float* L, char* ws) {
  u16* Lbf = (u16*)(ws + OFF_LBF);
  size_t i = ((size_t)blockIdx.x * 256 + threadIdx.x) * 4;
  float4 v = *(const float4*)(L + i);
  uint2v o;
  o.x = f2bf(v.x) | ((unsigned)f2bf(v.y) << 16);
  o.y = f2bf(v.z) | ((unsigned)f2bf(v.w) << 16);
  *(uint2v*)(Lbf + i) = o;
}

// ---------------- conv1 (MFMA): Yt[b][t*64+c][n] = b1[t] + sum x[b,n,c-1+dt,cin]*w1 ----------------
__global__ __launch_bounds__(256) void k_conv1(const float* x, const float* b1, char* ws) {
  __shared__ u16 Wl[6144];          // 12,288 B swizzled A
  __shared__ u16 Xt[128 * 104];     // rows padded to 104 elems (208 B) for bank balance
  int tid = threadIdx.x, bx = blockIdx.x;
  int nt = bx & 15, ct = (bx >> 4) & 63, b = bx >> 10;
  int n0 = nt * 128;
  const char* wsrc = ws + OFF_W1SW;
  for (int e = 0; e < 3; ++e) {
    int flat = e * 256 + tid;
    gld16(wsrc + flat * 16, (char*)Wl + flat * 16);
  }
  const float* xb = x + ((size_t)(b * 2048 + n0)) * 2048;
  for (int e = 0; e < 12; ++e) {
    int f = e * 256 + tid;
    int nl = f / 24, c4 = f % 24;
    int eo = ct * 32 - 32 + c4 * 4;
    uint2v o = {0u, 0u};
    if (eo >= 0 && eo < 2048) {
      float4 v = *(const float4*)(xb + (size_t)nl * 2048 + eo);
      o.x = f2bf(v.x) | ((unsigned)f2bf(v.y) << 16);
      o.y = f2bf(v.z) | ((unsigned)f2bf(v.w) << 16);
    }
    *(uint2v*)&Xt[nl * 104 + c4 * 4] = o;
  }
  __syncthreads();
  int w = tid >> 6, l = tid & 63, lm = l & 15, q = l >> 4;
  floatx4 zf = {0.f, 0.f, 0.f, 0.f};
  floatx4 acc[4][2];
  for (int s = 0; s < 4; ++s) for (int t = 0; t < 2; ++t) acc[s][t] = zf;
  for (int h = 0; h < 3; ++h) {
    bf16x8 a[4], bb[2];
    for (int s = 0; s < 4; ++s)
      a[s] = as_bf(*(const uint4v*)&Wl[(size_t)((h * 4 + s) * 64 + l) * 8]);
    for (int t = 0; t < 2; ++t) {
      int n = w * 32 + t * 16 + lm;
      bb[t] = as_bf(*(const uint4v*)&Xt[n * 104 + h * 32 + q * 8]);
    }
    for (int s = 0; s < 4; ++s)
      for (int t = 0; t < 2; ++t)
        acc[s][t] = __builtin_amdgcn_mfma_f32_16x16x32_bf16(a[s], bb[t], acc[s][t], 0, 0, 0);
  }
  u16* Yt = (u16*)(ws + OFF_YT);
  for (int s = 0; s < 4; ++s)
    for (int r = 0; r < 4; ++r) {
      int tch = s * 16 + q * 4 + r;
      float bias = b1[tch];
      for (int t = 0; t < 2; ++t) {
        int n = n0 + w * 32 + t * 16 + lm;
        Yt[(size_t)(b * 4096 + tch * 64 + ct) * 2048 + n] = f2bf(acc[s][t][r] + bias);
      }
    }
}

// ---------------- big GEMM: C[r][c] = sum_k P[r][k]*Q[c][k], K=2048, bf16, 128x128 tile ----------------
// LDS chunk-XOR swizzle: logical 16B chunk c of row r lives at physical chunk c ^ ((r>>1)&3).
// Staging keeps global_load_lds's contiguous lane->LDS mapping and permutes the GLOBAL source
// chunk instead; fragment reads add the matching offset. Spreads the 16-lane fragment read
// across 8 distinct 4-dword bank groups (2-way = free) instead of 2 (8-way = 2.9x).
__global__ __launch_bounds__(256) void k_gemm(const char* Pbase, const char* Qbase, char* Cbase,
                                              int MT, size_t P_bs, size_t Q_bs,
                                              size_t C_bs, size_t C_rs) {
  __shared__ u16 Pt[128 * 32];
  __shared__ u16 Qt[128 * 32];
  int tid = threadIdx.x, b = blockIdx.y;
  int rt = blockIdx.x % MT, ctl = blockIdx.x / MT;
  const char* Pp = Pbase + b * P_bs + (size_t)rt * 128 * 4096;
  const char* Qp = Qbase + b * Q_bs + (size_t)ctl * 128 * 4096;
  int w = tid >> 6, l = tid & 63, lm = l & 15, q = l >> 4;
  int wr = (w & 1) * 64, wc = (w >> 1) * 64;
  int qa = (q ^ ((lm >> 1) & 3)) * 8;   // swizzled chunk offset (row base % 16 == 0)
  floatx4 zf = {0.f, 0.f, 0.f, 0.f};
  floatx4 acc[4][4];
  for (int s = 0; s < 4; ++s) for (int t = 0; t < 4; ++t) acc[s][t] = zf;
  for (int k0 = 0; k0 < 2048; k0 += 32) {
    for (int e = 0; e < 2; ++e) {
      int flat = e * 256 + tid;
      int row = flat >> 2;
      int chunk = (flat & 3) ^ ((flat >> 3) & 3);   // = (flat&3) ^ ((row>>1)&3)
      gld16(Pp + (size_t)row * 4096 + k0 * 2 + chunk * 16, (char*)Pt + flat * 16);
      gld16(Qp + (size_t)row * 4096 + k0 * 2 + chunk * 16, (char*)Qt + flat * 16);
    }
    __syncthreads();
    bf16x8 a[4], bb[4];
    for (int s = 0; s < 4; ++s) a[s]  = as_bf(*(const uint4v*)&Pt[(wr + s * 16 + lm) * 32 + qa]);
    for (int t = 0; t < 4; ++t) bb[t] = as_bf(*(const uint4v*)&Qt[(wc + t * 16 + lm) * 32 + qa]);
    for (int s = 0; s < 4; ++s)
      for (int t = 0; t < 4; ++t)
        acc[s][t] = __builtin_amdgcn_mfma_f32_16x16x32_bf16(a[s], bb[t], acc[s][t], 0, 0, 0);
    __syncthreads();
  }
  for (int s = 0; s < 4; ++s)
    for (int r = 0; r < 4; ++r) {
      size_t rg = (size_t)rt * 128 + wr + s * 16 + q * 4 + r;
      char* crow = Cbase + b * C_bs + rg * C_rs;
      for (int t = 0; t < 4; ++t) {
        size_t cg = (size_t)ctl * 128 + wc + t * 16 + lm;
        *(u16*)(crow + cg * 2) = f2bf(acc[s][t][r]);
      }
    }
}

// ---------------- 64x64 LDS tile transpose: out[b][n][j] = in[b][j][n] (bf16) ----------------
__global__ __launch_bounds__(256) void k_transpose(const char* in, size_t in_bs,
                                                   char* out, size_t out_bs, size_t out_rs) {
  __shared__ u16 LT[64 * 74];
  int tid = threadIdx.x, b = blockIdx.y;
  int jt = blockIdx.x & 63, nt = blockIdx.x >> 6;
  int j0 = jt * 64, n0 = nt * 64;
  for (int e = 0; e < 2; ++e) {
    int flat = e * 256 + tid;
    int jl = flat >> 3, nc = (flat & 7) * 8;
    uint4v v = *(const uint4v*)(in + b * in_bs + (size_t)(j0 + jl) * 4096 + (n0 + nc) * 2);
    u16 u[8] = {(u16)(v.x & 0xffff), (u16)(v.x >> 16), (u16)(v.y & 0xffff), (u16)(v.y >> 16),
                (u16)(v.z & 0xffff), (u16)(v.z >> 16), (u16)(v.w & 0xffff), (u16)(v.w >> 16)};
    for (int i = 0; i < 8; ++i) LT[(nc + i) * 74 + jl] = u[i];
  }
  __syncthreads();
  for (int e = 0; e < 2; ++e) {
    int flat = e * 256 + tid;
    int nl = flat >> 3, jc = (flat & 7) * 8;
    unsigned p[4];
    for (int i = 0; i < 4; ++i) {
      unsigned lo = LT[nl * 74 + jc + 2 * i], hi = LT[nl * 74 + jc + 2 * i + 1];
      p[i] = lo | (hi << 16);
    }
    uint4v v = {p[0], p[1], p[2], p[3]};
    *(uint4v*)(out + b * out_bs + (size_t)(n0 + nl) * out_rs + (j0 + jc) * 2) = v;
  }
}

// ---------------- fused cheb-projection + conv2: out2[b,n,t',c'] (fp32, final layout) ----------------
__global__ __launch_bounds__(256) void k_fused(char* ws, float* dout, const float* b2) {
  __shared__ u16 Gs[12288];          // 24,576 B one source's swizzled G
  __shared__ u16 Brow[2][4752];      // 66 groups * (64 elems + 16B pad) per row, 2 rows
  int tid = threadIdx.x;
  int np = blockIdx.x, b = blockIdx.y;
  size_t row0 = (size_t)b * 2048 + np * 2;
  if (tid < 144) {                   // zero LDS guard groups (conv SAME padding)
    int r = tid / 72, o = tid % 72;
    Brow[r][o] = 0; Brow[r][65 * 72 + o] = 0;
  }
  int w = tid >> 6, l = tid & 63, lm = l & 15, q = l >> 4;
  int n_loc = w & 1, thalf = w >> 1;
  floatx4 zf = {0.f, 0.f, 0.f, 0.f};
  floatx4 acc[2][4];
  for (int tr = 0; tr < 2; ++tr) for (int tc = 0; tc < 4; ++tc) acc[tr][tc] = zf;
  for (int s = 0; s < 3; ++s) {
    for (int e = 0; e < 6; ++e) {
      int flat = e * 256 + tid;
      gld16(ws + OFF_GSW + (size_t)s * 24576 + flat * 16, (char*)Gs + flat * 16);
    }
    for (int e = 0; e < 4; ++e) {
      int ci = e * 256 + tid;              // 0..1023
      int rl = ci >> 9, c = ci & 511;
      size_t rid = row0 + rl;
      const char* src;
      if (s == 0)      src = (const char*)dout + rid * 16384;           // Yn
      else if (s == 1) src = ws + OFF_T1N + rid * 8192;                 // T1n
      else             src = (const char*)dout + rid * 16384 + 8192;    // Un
      uint4v v = *(const uint4v*)(src + c * 16);
      int e0 = 64 + c * 8;
      *(uint4v*)&Brow[rl][(e0 >> 6) * 72 + (e0 & 63)] = v;
    }
    __syncthreads();
    for (int h = 0; h < 6; ++h) {
      int dt = h >> 1, chalf = h & 1;
      bf16x8 a[2], bb[4];
      for (int tr = 0; tr < 2; ++tr)
        a[tr] = as_bf(*(const uint4v*)&Gs[(size_t)((h * 4 + thalf * 2 + tr) * 64 + l) * 8]);
      for (int tc = 0; tc < 4; ++tc) {
        int cp = tc * 16 + lm;
        int ctil = cp + dt;
        bb[tc] = as_bf(*(const uint4v*)&Brow[n_loc][ctil * 72 + chalf * 32 + q * 8]);
      }
      for (int tr = 0; tr < 2; ++tr)
        for (int tc = 0; tc < 4; ++tc)
          acc[tr][tc] = __builtin_amdgcn_mfma_f32_16x16x32_bf16(a[tr], bb[tc], acc[tr][tc], 0, 0, 0);
    }
    __syncthreads();
  }
  const float* P = (const float*)(ws + OFF_P);
  float* orow = dout + (row0 + n_loc) * 4096;
  for (int tr = 0; tr < 2; ++tr)
    for (int r = 0; r < 4; ++r) {
      int tp = thalf * 32 + tr * 16 + q * 4 + r;
      float base = b2[tp] + P[tp * 3 + 1];
      for (int tc = 0; tc < 4; ++tc) {
        int cp = tc * 16 + lm;
        float bias = base + (cp > 0 ? P[tp * 3] : 0.f) + (cp < 63 ? P[tp * 3 + 2] : 0.f);
        orow[tp * 64 + cp] = acc[tr][tc][r] + bias;
      }
    }
}

// ---------------- BN stats: per-block partials per channel ----------------
__global__ __launch_bounds__(256) void k_stats(const float* dout, char* ws) {
  __shared__ float ls[256][8];
  int tid = threadIdx.x;
  size_t base = (size_t)blockIdx.x * 16384 + tid * 4;
  float s0 = 0, s1 = 0, s2 = 0, s3 = 0, t0 = 0, t1 = 0, t2 = 0, t3 = 0;
  for (int it = 0; it < 16; ++it) {
    float4 v = *(const float4*)(dout + base + (size_t)it * 1024);
    s0 += v.x; s1 += v.y; s2 += v.z; s3 += v.w;
    t0 += v.x * v.x; t1 += v.y * v.y; t2 += v.z * v.z; t3 += v.w * v.w;
  }
  ls[tid][0] = s0; ls[tid][1] = s1; ls[tid][2] = s2; ls[tid][3] = s3;
  ls[tid][4] = t0; ls[tid][5] = t1; ls[tid][6] = t2; ls[tid][7] = t3;
  __syncthreads();
  if (tid < 64) {
    int g = tid >> 2, sl = tid & 3;
    float S = 0, S2 = 0;
    for (int j = 0; j < 16; ++j) { S += ls[g + j * 16][sl]; S2 += ls[g + j * 16][4 + sl]; }
    ((float*)(ws + OFF_S))[(size_t)tid * 4096 + blockIdx.x] = S;
    ((float*)(ws + OFF_S2))[(size_t)tid * 4096 + blockIdx.x] = S2;
  }
}

__global__ __launch_bounds__(256) void k_statsf(char* ws, const float* gamma, const float* beta) {
  __shared__ float red[256];
  int c = blockIdx.x, tid = threadIdx.x;
  const float* S  = (const float*)(ws + OFF_S)  + (size_t)c * 4096;
  const float* S2 = (const float*)(ws + OFF_S2) + (size_t)c * 4096;
  float a = 0, bsum = 0;
  for (int j = 0; j < 16; ++j) { a += S[tid + j * 256]; bsum += S2[tid + j * 256]; }
  red[tid] = a; __syncthreads();
  for (int st = 128; st > 0; st >>= 1) { if (tid < st) red[tid] += red[tid + st]; __syncthreads(); }
  float Ssum = red[0]; __syncthreads();
  red[tid] = bsum; __syncthreads();
  for (int st = 128; st > 0; st >>= 1) { if (tid < st) red[tid] += red[tid + st]; __syncthreads(); }
  if (tid == 0) {
    float S2sum = red[0];
    float mean = Ssum / 1048576.f;
    float var = S2sum / 1048576.f - mean * mean;
    float inv = rsqrtf(var + 1e-5f);
    float A = gamma[c] * inv;
    float* AB = (float*)(ws + OFF_AB);
    AB[c] = A; AB[64 + c] = beta[c] - mean * A;
  }
}

__global__ __launch_bounds__(256) void k_bn(float* dout, const char* ws) {
  __shared__ float AB[128];
  int tid = threadIdx.x;
  if (tid < 128) AB[tid] = ((const float*)(ws + OFF_AB))[tid];
  __syncthreads();
  size_t i = ((size_t)blockIdx.x * 256 + tid) * 4;
  int c0 = (tid * 4) & 63;
  float4 v = *(const float4*)(dout + i);
  v.x = fmaxf(0.f, v.x * AB[c0]     + AB[64 + c0]);
  v.y = fmaxf(0.f, v.y * AB[c0 + 1] + AB[64 + c0 + 1]);
  v.z = fmaxf(0.f, v.z * AB[c0 + 2] + AB[64 + c0 + 2]);
  v.w = fmaxf(0.f, v.w * AB[c0 + 3] + AB[64 + c0 + 3]);
  *(float4*)(dout + i) = v;
}

extern "C" void kernel_launch(void* const* d_in, const int* in_sizes, int n_in,
                              void* d_out, int out_size, void* d_ws, size_t ws_size,
                              hipStream_t stream) {
  const float* x   = (const float*)d_in[0];
  const float* L   = (const float*)d_in[1];
  const float* w1  = (const float*)d_in[2];
  const float* b1  = (const float*)d_in[3];
  const float* chw = (const float*)d_in[4];
  const float* chb = (const float*)d_in[5];
  const float* w2  = (const float*)d_in[6];
  const float* b2  = (const float*)d_in[7];
  const float* gam = (const float*)d_in[8];
  const float* bet = (const float*)d_in[9];
  char* ws = (char*)d_ws;
  float* out = (float*)d_out;

  k_prep1<<<1, 256, 0, stream>>>(w1, w2, chb, ws);
  k_prepG<<<192, 256, 0, stream>>>(w2, chw, ws);
  k_castL<<<4096, 256, 0, stream>>>(L, ws);
  k_conv1<<<8192, 256, 0, stream>>>(x, b1, ws);
  // GEMM1: T1t[b][j][m] = sum_n Yt[b][j][n] * L[m][n]
  k_gemm<<<dim3(512, 8), 256, 0, stream>>>(ws + OFF_YT, ws + OFF_LBF, ws + OFF_T1T,
                                           32, (size_t)16777216, (size_t)0,
                                           (size_t)16777216, (size_t)4096);
  // GEMM2: Un[b][m'][j] = sum_m L[m'][m] * T1t[b][j][m]  -> d_out rows, second 8KB half
  k_gemm<<<dim3(512, 8), 256, 0, stream>>>(ws + OFF_LBF, ws + OFF_T1T, (char*)d_out + 8192,
                                           16, (size_t)0, (size_t)16777216,
                                           (size_t)33554432, (size_t)16384);
  // Yt -> Yn (d_out rows, first 8KB half)
  k_transpose<<<dim3(2048, 8), 256, 0, stream>>>(ws + OFF_YT, (size_t)16777216,
                                                 (char*)d_out, (size_t)33554432, (size_t)16384);
  // T1t -> T1n (ws @0, over dead Yt)
  k_transpose<<<dim3(2048, 8), 256, 0, stream>>>(ws + OFF_T1T, (size_t)16777216,
                                                 ws + OFF_T1N, (size_t)16777216, (size_t)8192);
  k_fused<<<dim3(1024, 8), 256, 0, stream>>>(ws, out, b2);
  k_stats<<<4096, 256, 0, stream>>>(out, ws);
  k_statsf<<<64, 256, 0, stream>>>(ws, gam, bet);
  k_bn<<<65536, 256, 0, stream>>>(out, ws);
}

// Round 3
// 1346.367 us; speedup vs baseline: 1.1345x; 1.0895x over previous
//
#include <hip/hip_runtime.h>
#include <cstdint>

typedef __bf16 bf16x8 __attribute__((ext_vector_type(8)));
typedef float floatx4 __attribute__((ext_vector_type(4)));
typedef unsigned int uint4v __attribute__((ext_vector_type(4)));
typedef unsigned int uint2v __attribute__((ext_vector_type(2)));
using u16 = unsigned short;

#define DEVFN static __device__ __forceinline__

// ---------------- workspace layout (bytes) ----------------
// required ws_size >= ~281 MB (round-1/2 used ~285 MB and passed)
#define SZ_BIG   134217728ull                 // 8*4096*2048 bf16
#define OFF_YT   0ull                         // Yt [b][j=(t,c)][n] bf16
#define OFF_T1N  0ull                         // T1n reuses Yt region (Yt dead by then)
#define OFF_T1T  SZ_BIG                       // T1t [b][j][m] bf16; later reused as bf16 preBN
#define OFF_PB   SZ_BIG                       // preBN bf16 [16384 rows][4096] (over dead T1t)
#define OFF_LBF  (2ull*SZ_BIG)                // L bf16 [m][n]
#define OFF_W1SW (OFF_LBF + 8388608ull)       // conv1 A-operand, MFMA-frag-swizzled, 12288 B
#define OFF_GSW  (OFF_W1SW + 12288ull)        // fused-stage G, frag-swizzled, 3*24576 B
#define OFF_P    (OFF_GSW + 73728ull)         // P[t'][dt] cheb_b feed-through, 768 B
#define OFF_AB   (OFF_P + 1024ull)            // BN scale/shift, 512 B
#define OFF_S    (OFF_P + 2048ull)            // stat partials [2][64][8192] f32 = 4 MB

DEVFN u16 f2bf(float f) {
  unsigned u = __builtin_bit_cast(unsigned, f);
  unsigned r = u + 0x7fffu + ((u >> 16) & 1u);   // RNE
  return (u16)(r >> 16);
}
DEVFN bf16x8 as_bf(uint4v v) { union { uint4v u; bf16x8 b; } x; x.u = v; return x.b; }

DEVFN void gld16(const void* g, void* l) {
  __builtin_amdgcn_global_load_lds(
      (const __attribute__((address_space(1))) void*)(uintptr_t)g,
      (__attribute__((address_space(3))) void*)(unsigned)(uintptr_t)l,
      16, 0, 0);
}

// ---------------- prep: swizzle w1 into MFMA-A order; cheb_b feed-through P ----------------
__global__ __launch_bounds__(256) void k_prep1(const float* w1, const float* w2,
                                               const float* chb, char* ws) {
  u16* W1sw = (u16*)(ws + OFF_W1SW);
  float* P  = (float*)(ws + OFF_P);
  int tid = threadIdx.x;
  for (int it = 0; it < 24; ++it) {
    int idx = it * 256 + tid;                    // < 6144
    int i = idx & 7, lane = (idx >> 3) & 63, trow = (idx >> 9) & 3, h = idx >> 11;
    int m = trow * 16 + (lane & 15);
    int k = h * 32 + (lane >> 4) * 8 + i;        // < 96
    W1sw[idx] = f2bf(w1[(m * 32 + (k & 31)) * 3 + (k >> 5)]);
  }
  if (tid < 192) {
    int tp = tid / 3, dt = tid % 3;
    float s = 0.f;
    for (int d = 0; d < 64; ++d) s += w2[(tp * 64 + d) * 3 + dt] * chb[d];
    P[tid] = s;
  }
}

// ---------------- prep: G_i[t'][dt*64+c] = sum_d w2[t',d,dt]*A_i[c,d], frag-swizzled ----------------
__global__ __launch_bounds__(256) void k_prepG(const float* w2, const float* chw, char* ws) {
  u16* Gsw = (u16*)(ws + OFF_GSW);
  int s = blockIdx.x >> 6, tp = blockIdx.x & 63;
  int tid = threadIdx.x;
  if (tid >= 192) return;
  int dt = tid >> 6, c = tid & 63;
  float acc = 0.f;
  for (int d = 0; d < 64; ++d) {
    float a;
    if (s == 0)      a = chw[(0 * 64 + c) * 64 + d] - chw[(2 * 64 + c) * 64 + d];
    else if (s == 1) a = chw[(1 * 64 + c) * 64 + d];
    else             a = 2.f * chw[(2 * 64 + c) * 64 + d];
    acc += w2[(tp * 64 + d) * 3 + dt] * a;
  }
  int h = tid >> 5, k32 = tid & 31;
  int lane = (k32 >> 3) * 16 + (tp & 15), trow = tp >> 4;
  Gsw[(size_t)(((s * 6 + h) * 4 + trow) * 64 + lane) * 8 + (k32 & 7)] = f2bf(acc);
}

// ---------------- cast L -> bf16 ----------------
__global__ __launch_bounds__(256) void k_castL(const float* L, char* ws) {
  u16* Lbf = (u16*)(ws + OFF_LBF);
  size_t i = ((size_t)blockIdx.x * 256 + threadIdx.x) * 4;
  float4 v = *(const float4*)(L + i);
  uint2v o;
  o.x = f2bf(v.x) | ((unsigned)f2bf(v.y) << 16);
  o.y = f2bf(v.z) | ((unsigned)f2bf(v.w) << 16);
  *(uint2v*)(Lbf + i) = o;
}

// ---------------- conv1 (MFMA): Yt[b][t*64+c][n] = b1[t] + sum x[b,n,c-1+dt,cin]*w1 ----------------
__global__ __launch_bounds__(256) void k_conv1(const float* x, const float* b1, char* ws) {
  __shared__ u16 Wl[6144];          // 12,288 B swizzled A
  __shared__ u16 Xt[128 * 104];     // rows padded to 104 elems (208 B) for bank balance
  int tid = threadIdx.x, bx = blockIdx.x;
  int nt = bx & 15, ct = (bx >> 4) & 63, b = bx >> 10;
  int n0 = nt * 128;
  const char* wsrc = ws + OFF_W1SW;
  for (int e = 0; e < 3; ++e) {
    int flat = e * 256 + tid;
    gld16(wsrc + flat * 16, (char*)Wl + flat * 16);
  }
  const float* xb = x + ((size_t)(b * 2048 + n0)) * 2048;
  for (int e = 0; e < 12; ++e) {
    int f = e * 256 + tid;
    int nl = f / 24, c4 = f % 24;
    int eo = ct * 32 - 32 + c4 * 4;
    uint2v o = {0u, 0u};
    if (eo >= 0 && eo < 2048) {
      float4 v = *(const float4*)(xb + (size_t)nl * 2048 + eo);
      o.x = f2bf(v.x) | ((unsigned)f2bf(v.y) << 16);
      o.y = f2bf(v.z) | ((unsigned)f2bf(v.w) << 16);
    }
    *(uint2v*)&Xt[nl * 104 + c4 * 4] = o;
  }
  __syncthreads();
  int w = tid >> 6, l = tid & 63, lm = l & 15, q = l >> 4;
  floatx4 zf = {0.f, 0.f, 0.f, 0.f};
  floatx4 acc[4][2];
  for (int s = 0; s < 4; ++s) for (int t = 0; t < 2; ++t) acc[s][t] = zf;
  for (int h = 0; h < 3; ++h) {
    bf16x8 a[4], bb[2];
    for (int s = 0; s < 4; ++s)
      a[s] = as_bf(*(const uint4v*)&Wl[(size_t)((h * 4 + s) * 64 + l) * 8]);
    for (int t = 0; t < 2; ++t) {
      int n = w * 32 + t * 16 + lm;
      bb[t] = as_bf(*(const uint4v*)&Xt[n * 104 + h * 32 + q * 8]);
    }
    for (int s = 0; s < 4; ++s)
      for (int t = 0; t < 2; ++t)
        acc[s][t] = __builtin_amdgcn_mfma_f32_16x16x32_bf16(a[s], bb[t], acc[s][t], 0, 0, 0);
  }
  u16* Yt = (u16*)(ws + OFF_YT);
  for (int s = 0; s < 4; ++s)
    for (int r = 0; r < 4; ++r) {
      int tch = s * 16 + q * 4 + r;
      float bias = b1[tch];
      for (int t = 0; t < 2; ++t) {
        int n = n0 + w * 32 + t * 16 + lm;
        Yt[(size_t)(b * 4096 + tch * 64 + ct) * 2048 + n] = f2bf(acc[s][t][r] + bias);
      }
    }
}

// ---------------- big GEMM: C[r][c] = sum_k P[r][k]*Q[c][k], K=2048, bf16 ----------------
// BK=64 (halves barrier drains vs BK=32; LDS 2x16KB keeps >=3 blocks/CU).
// XOR-8 chunk swizzle: row stride is 128 B so logical 16B chunk c of row r lives at
// physical chunk c ^ (r&7); staging permutes the GLOBAL source chunk (global_load_lds
// requires contiguous lane->LDS), fragment reads XOR with lm&7. 2-way banks = free.
__global__ __launch_bounds__(256) void k_gemm(const char* Pbase, const char* Qbase, char* Cbase,
                                              int MT, size_t P_bs, size_t Q_bs,
                                              size_t C_bs, size_t C_rs) {
  __shared__ u16 Pt[128 * 64];
  __shared__ u16 Qt[128 * 64];
  int tid = threadIdx.x, b = blockIdx.y;
  int rt = blockIdx.x % MT, ctl = blockIdx.x / MT;
  const char* Pp = Pbase + b * P_bs + (size_t)rt * 128 * 4096;
  const char* Qp = Qbase + b * Q_bs + (size_t)ctl * 128 * 4096;
  int w = tid >> 6, l = tid & 63, lm = l & 15, q = l >> 4;
  int wr = (w & 1) * 64, wc = (w >> 1) * 64;
  int x7 = lm & 7;
  floatx4 zf = {0.f, 0.f, 0.f, 0.f};
  floatx4 acc[4][4];
  for (int s = 0; s < 4; ++s) for (int t = 0; t < 4; ++t) acc[s][t] = zf;
  for (int k0 = 0; k0 < 2048; k0 += 64) {
    for (int e = 0; e < 4; ++e) {
      int flat = e * 256 + tid;                 // 0..1023
      int row = flat >> 3, c = flat & 7;
      int sc = c ^ (row & 7);
      gld16(Pp + (size_t)row * 4096 + k0 * 2 + sc * 16, (char*)Pt + flat * 16);
      gld16(Qp + (size_t)row * 4096 + k0 * 2 + sc * 16, (char*)Qt + flat * 16);
    }
    __syncthreads();
    for (int ks = 0; ks < 2; ++ks) {
      int co = ((ks * 4 + q) ^ x7) * 8;
      bf16x8 a[4], bb[4];
      for (int s = 0; s < 4; ++s) a[s]  = as_bf(*(const uint4v*)&Pt[(wr + s * 16 + lm) * 64 + co]);
      for (int t = 0; t < 4; ++t) bb[t] = as_bf(*(const uint4v*)&Qt[(wc + t * 16 + lm) * 64 + co]);
      for (int s = 0; s < 4; ++s)
        for (int t = 0; t < 4; ++t)
          acc[s][t] = __builtin_amdgcn_mfma_f32_16x16x32_bf16(a[s], bb[t], acc[s][t], 0, 0, 0);
    }
    __syncthreads();
  }
  for (int s = 0; s < 4; ++s)
    for (int r = 0; r < 4; ++r) {
      size_t rg = (size_t)rt * 128 + wr + s * 16 + q * 4 + r;
      char* crow = Cbase + b * C_bs + rg * C_rs;
      for (int t = 0; t < 4; ++t) {
        size_t cg = (size_t)ctl * 128 + wc + t * 16 + lm;
        *(u16*)(crow + cg * 2) = f2bf(acc[s][t][r]);
      }
    }
}

// ---------------- 64x64 LDS tile transpose: out[b][n][j] = in[b][j][n] (bf16) ----------------
__global__ __launch_bounds__(256) void k_transpose(const char* in, size_t in_bs,
                                                   char* out, size_t out_bs, size_t out_rs) {
  __shared__ u16 LT[64 * 74];
  int tid = threadIdx.x, b = blockIdx.y;
  int jt = blockIdx.x & 63, nt = blockIdx.x >> 6;
  int j0 = jt * 64, n0 = nt * 64;
  for (int e = 0; e < 2; ++e) {
    int flat = e * 256 + tid;
    int jl = flat >> 3, nc = (flat & 7) * 8;
    uint4v v = *(const uint4v*)(in + b * in_bs + (size_t)(j0 + jl) * 4096 + (n0 + nc) * 2);
    u16 u[8] = {(u16)(v.x & 0xffff), (u16)(v.x >> 16), (u16)(v.y & 0xffff), (u16)(v.y >> 16),
                (u16)(v.z & 0xffff), (u16)(v.z >> 16), (u16)(v.w & 0xffff), (u16)(v.w >> 16)};
    for (int i = 0; i < 8; ++i) LT[(nc + i) * 74 + jl] = u[i];
  }
  __syncthreads();
  for (int e = 0; e < 2; ++e) {
    int flat = e * 256 + tid;
    int nl = flat >> 3, jc = (flat & 7) * 8;
    unsigned p[4];
    for (int i = 0; i < 4; ++i) {
      unsigned lo = LT[nl * 74 + jc + 2 * i], hi = LT[nl * 74 + jc + 2 * i + 1];
      p[i] = lo | (hi << 16);
    }
    uint4v v = {p[0], p[1], p[2], p[3]};
    *(uint4v*)(out + b * out_bs + (size_t)(n0 + nl) * out_rs + (j0 + jc) * 2) = v;
  }
}

// ---------------- fused cheb-projection + conv2 -> bf16 preBN + per-block BN partials ----------------
__global__ __launch_bounds__(256) void k_fused(char* ws, const float* dout_src, const float* b2) {
  __shared__ u16 Gs[12288];          // 24,576 B one source's swizzled G
  __shared__ u16 Brow[2][4752];      // 66 groups * (64 elems + 16B pad) per row, 2 rows
  __shared__ float SS[4][64][4];
  __shared__ float SQ[4][64][4];
  int tid = threadIdx.x;
  int np = blockIdx.x, b = blockIdx.y;
  size_t row0 = (size_t)b * 2048 + np * 2;
  if (tid < 144) {                   // zero LDS guard groups (conv SAME padding)
    int r = tid / 72, o = tid % 72;
    Brow[r][o] = 0; Brow[r][65 * 72 + o] = 0;
  }
  int w = tid >> 6, l = tid & 63, lm = l & 15, q = l >> 4;
  int n_loc = w & 1, thalf = w >> 1;
  floatx4 zf = {0.f, 0.f, 0.f, 0.f};
  floatx4 acc[2][4];
  for (int tr = 0; tr < 2; ++tr) for (int tc = 0; tc < 4; ++tc) acc[tr][tc] = zf;
  for (int s = 0; s < 3; ++s) {
    for (int e = 0; e < 6; ++e) {
      int flat = e * 256 + tid;
      gld16(ws + OFF_GSW + (size_t)s * 24576 + flat * 16, (char*)Gs + flat * 16);
    }
    for (int e = 0; e < 4; ++e) {
      int ci = e * 256 + tid;              // 0..1023
      int rl = ci >> 9, c = ci & 511;
      size_t rid = row0 + rl;
      const char* src;
      if (s == 0)      src = (const char*)dout_src + rid * 16384;           // Yn
      else if (s == 1) src = ws + OFF_T1N + rid * 8192;                     // T1n
      else             src = (const char*)dout_src + rid * 16384 + 8192;    // Un
      uint4v v = *(const uint4v*)(src + c * 16);
      int e0 = 64 + c * 8;
      *(uint4v*)&Brow[rl][(e0 >> 6) * 72 + (e0 & 63)] = v;
    }
    __syncthreads();
    for (int h = 0; h < 6; ++h) {
      int dt = h >> 1, chalf = h & 1;
      bf16x8 a[2], bb[4];
      for (int tr = 0; tr < 2; ++tr)
        a[tr] = as_bf(*(const uint4v*)&Gs[(size_t)((h * 4 + thalf * 2 + tr) * 64 + l) * 8]);
      for (int tc = 0; tc < 4; ++tc) {
        int cp = tc * 16 + lm;
        int ctil = cp + dt;
        bb[tc] = as_bf(*(const uint4v*)&Brow[n_loc][ctil * 72 + chalf * 32 + q * 8]);
      }
      for (int tr = 0; tr < 2; ++tr)
        for (int tc = 0; tc < 4; ++tc)
          acc[tr][tc] = __builtin_amdgcn_mfma_f32_16x16x32_bf16(a[tr], bb[tc], acc[tr][tc], 0, 0, 0);
    }
    __syncthreads();
  }
  const float* P = (const float*)(ws + OFF_P);
  u16* prow = (u16*)(ws + OFF_PB) + (row0 + n_loc) * 4096;
  float sloc[4] = {0.f, 0.f, 0.f, 0.f}, sqloc[4] = {0.f, 0.f, 0.f, 0.f};
  for (int tr = 0; tr < 2; ++tr)
    for (int r = 0; r < 4; ++r) {
      int tp = thalf * 32 + tr * 16 + q * 4 + r;
      float base = b2[tp] + P[tp * 3 + 1];
      for (int tc = 0; tc < 4; ++tc) {
        int cp = tc * 16 + lm;
        float bias = base + (cp > 0 ? P[tp * 3] : 0.f) + (cp < 63 ? P[tp * 3 + 2] : 0.f);
        float v = acc[tr][tc][r] + bias;
        prow[tp * 64 + cp] = f2bf(v);
        sloc[tc] += v; sqloc[tc] += v * v;
      }
    }
  for (int tc = 0; tc < 4; ++tc) { SS[w][l][tc] = sloc[tc]; SQ[w][l][tc] = sqloc[tc]; }
  __syncthreads();
  if (tid < 128) {
    int c = tid & 63, which = tid >> 6;
    float s = 0.f;
    for (int ww = 0; ww < 4; ++ww)
      for (int qq = 0; qq < 4; ++qq)
        s += which ? SQ[ww][qq * 16 + (c & 15)][c >> 4] : SS[ww][qq * 16 + (c & 15)][c >> 4];
    float* Sp = (float*)(ws + OFF_S);
    Sp[((size_t)which * 64 + c) * 8192 + (size_t)b * 1024 + np] = s;
  }
}

// ---------------- BN stat finalize: reduce 8192 partials per channel ----------------
__global__ __launch_bounds__(256) void k_statsf(char* ws, const float* gamma, const float* beta) {
  __shared__ float red[256];
  int c = blockIdx.x, tid = threadIdx.x;
  const float* S  = (const float*)(ws + OFF_S) + (size_t)c * 8192;
  const float* S2 = S + 64 * 8192;
  float a = 0.f, bsum = 0.f;
  for (int j = 0; j < 32; ++j) { a += S[tid + j * 256]; bsum += S2[tid + j * 256]; }
  red[tid] = a; __syncthreads();
  for (int st = 128; st > 0; st >>= 1) { if (tid < st) red[tid] += red[tid + st]; __syncthreads(); }
  float Ssum = red[0]; __syncthreads();
  red[tid] = bsum; __syncthreads();
  for (int st = 128; st > 0; st >>= 1) { if (tid < st) red[tid] += red[tid + st]; __syncthreads(); }
  if (tid == 0) {
    float S2sum = red[0];
    float mean = Ssum / 1048576.f;
    float var = S2sum / 1048576.f - mean * mean;
    float inv = rsqrtf(var + 1e-5f);
    float A = gamma[c] * inv;
    float* AB = (float*)(ws + OFF_AB);
    AB[c] = A; AB[64 + c] = beta[c] - mean * A;
  }
}

// ---------------- BN apply + relu: bf16 preBN -> f32 out ----------------
__global__ __launch_bounds__(256) void k_bn(float* dout, const char* ws) {
  __shared__ float AB[128];
  int tid = threadIdx.x;
  if (tid < 128) AB[tid] = ((const float*)(ws + OFF_AB))[tid];
  __syncthreads();
  const u16* PB = (const u16*)(ws + OFF_PB);
  size_t i = ((size_t)blockIdx.x * 256 + tid) * 8;
  int c0 = (int)(i & 63);
  uint4v v = *(const uint4v*)(PB + i);
  unsigned uu[4] = {v.x, v.y, v.z, v.w};
  float f[8];
  for (int j = 0; j < 4; ++j) {
    f[2 * j]     = __builtin_bit_cast(float, uu[j] << 16);
    f[2 * j + 1] = __builtin_bit_cast(float, uu[j] & 0xffff0000u);
  }
  float4 o0, o1;
  o0.x = fmaxf(0.f, f[0] * AB[c0]     + AB[64 + c0]);
  o0.y = fmaxf(0.f, f[1] * AB[c0 + 1] + AB[64 + c0 + 1]);
  o0.z = fmaxf(0.f, f[2] * AB[c0 + 2] + AB[64 + c0 + 2]);
  o0.w = fmaxf(0.f, f[3] * AB[c0 + 3] + AB[64 + c0 + 3]);
  o1.x = fmaxf(0.f, f[4] * AB[c0 + 4] + AB[64 + c0 + 4]);
  o1.y = fmaxf(0.f, f[5] * AB[c0 + 5] + AB[64 + c0 + 5]);
  o1.z = fmaxf(0.f, f[6] * AB[c0 + 6] + AB[64 + c0 + 6]);
  o1.w = fmaxf(0.f, f[7] * AB[c0 + 7] + AB[64 + c0 + 7]);
  *(float4*)(dout + i) = o0;
  *(float4*)(dout + i + 4) = o1;
}

extern "C" void kernel_launch(void* const* d_in, const int* in_sizes, int n_in,
                              void* d_out, int out_size, void* d_ws, size_t ws_size,
                              hipStream_t stream) {
  const float* x   = (const float*)d_in[0];
  const float* L   = (const float*)d_in[1];
  const float* w1  = (const float*)d_in[2];
  const float* b1  = (const float*)d_in[3];
  const float* chw = (const float*)d_in[4];
  const float* chb = (const float*)d_in[5];
  const float* w2  = (const float*)d_in[6];
  const float* b2  = (const float*)d_in[7];
  const float* gam = (const float*)d_in[8];
  const float* bet = (const float*)d_in[9];
  char* ws = (char*)d_ws;
  float* out = (float*)d_out;

  k_prep1<<<1, 256, 0, stream>>>(w1, w2, chb, ws);
  k_prepG<<<192, 256, 0, stream>>>(w2, chw, ws);
  k_castL<<<4096, 256, 0, stream>>>(L, ws);
  k_conv1<<<8192, 256, 0, stream>>>(x, b1, ws);
  // GEMM1: T1t[b][j][m] = sum_n Yt[b][j][n] * L[m][n]
  k_gemm<<<dim3(512, 8), 256, 0, stream>>>(ws + OFF_YT, ws + OFF_LBF, ws + OFF_T1T,
                                           32, (size_t)16777216, (size_t)0,
                                           (size_t)16777216, (size_t)4096);
  // GEMM2: Un[b][m'][j] = sum_m L[m'][m] * T1t[b][j][m]  -> d_out rows, second 8KB half
  k_gemm<<<dim3(512, 8), 256, 0, stream>>>(ws + OFF_LBF, ws + OFF_T1T, (char*)d_out + 8192,
                                           16, (size_t)0, (size_t)16777216,
                                           (size_t)33554432, (size_t)16384);
  // Yt -> Yn (d_out rows, first 8KB half)
  k_transpose<<<dim3(2048, 8), 256, 0, stream>>>(ws + OFF_YT, (size_t)16777216,
                                                 (char*)d_out, (size_t)33554432, (size_t)16384);
  // T1t -> T1n (ws @0, over dead Yt)
  k_transpose<<<dim3(2048, 8), 256, 0, stream>>>(ws + OFF_T1T, (size_t)16777216,
                                                 ws + OFF_T1N, (size_t)16777216, (size_t)8192);
  // fused: reads Yn/Un (d_out) + T1n (ws@0); writes bf16 preBN over dead T1t + BN partials
  k_fused<<<dim3(1024, 8), 256, 0, stream>>>(ws, (const float*)d_out, b2);
  k_statsf<<<64, 256, 0, stream>>>(ws, gam, bet);
  k_bn<<<32768, 256, 0, stream>>>(out, ws);
}